// Round 5
// baseline (32.228 us; speedup 1.0000x reference)
//
#include <hip/hip_runtime.h>

#define NEG (-1e6f)

static constexpr int B = 32, Q = 64, K = 512, H = 64, V = 64;
static constexpr float C2LE = 2.8853900817779268f;   // 2*log2(e)
static constexpr float L2E  = 1.4426950408889634f;   // log2(e)

typedef __attribute__((ext_vector_type(8))) short bf16x8;
typedef __attribute__((ext_vector_type(4))) float f32x4;

__device__ __forceinline__ float fexp2(float x) { return __builtin_amdgcn_exp2f(x); }
__device__ __forceinline__ float frcp(float x)  { return __builtin_amdgcn_rcpf(x); }

__device__ __forceinline__ short f2bf(float f) {  // RNE f32 -> bf16
  union { float f; unsigned u; } v; v.f = f;
  unsigned r = v.u + 0x7fffu + ((v.u >> 16) & 1u);
  return (short)(r >> 16);
}

__device__ __forceinline__ float rdlane(float v, int l) {
  return __uint_as_float(__builtin_amdgcn_readlane(__float_as_uint(v), l));
}

// ---- MFMA projections + fused exponentials.
// Query rows -> qAR[row*H+h] = { -2*wv_h*e^{-2q}, e^{-2q} }   (row-major)
// Key rows   -> EkT[b][h][k] = e^{2k}                          (TRANSPOSED)
// wv_h*tanh(q+k) = wv_h + A*rcp(R+E); constant sum(wv) dropped (softmax shift-inv).
// Clamp +-15 before exp (tanh saturated there) so nothing overflows.
// MFMA 16x16x32 bf16 (m89/m91): A: row=l&15, k=(l>>4)*8+j; B: col=l&15 same k;
// C/D: col=l&15, row=(l>>4)*4+reg.  Swapping operands transposes D -> for key
// rows D[h][k] comes out h-major and the store is fully packed 64B lines.
__global__ __launch_bounds__(256) void proj_kernel(
    const float* __restrict__ queries, const float* __restrict__ keys,
    const float* __restrict__ Wq, const float* __restrict__ Wk,
    const float* __restrict__ wv,
    float2* __restrict__ qAR, float* __restrict__ EkT)
{
  __shared__ float Wl[64 * 65];                    // +1 pad: <=2-way conflicts (free)
  const int tid = threadIdx.x;
  const int lane = tid & 63;
  const int wave = __builtin_amdgcn_readfirstlane(tid >> 6);
  const int stripe0 = blockIdx.x * 4;              // 16-row stripes
  const bool isQ = stripe0 < 128;                  // 2048 q-rows (block-uniform)
  const float* Wsrc = isQ ? Wq : Wk;

  #pragma unroll
  for (int i = 0; i < 16; ++i) {                   // stage W (coalesced)
    const int idx = tid + i * 256;
    Wl[(idx >> 6) * 65 + (idx & 63)] = Wsrc[idx];
  }
  __syncthreads();

  const int row0 = (stripe0 + wave) * 16;
  const int r = lane & 15, g = lane >> 4;          // tile-row / k-group
  const float* xbase = isQ ? (queries + (size_t)row0 * H)
                           : (keys + (size_t)(row0 - 2048) * H);

  bf16x8 afr[2];
  #pragma unroll
  for (int kb = 0; kb < 2; ++kb) {                 // X frags: 8 contiguous k per lane
    const float* px = xbase + (size_t)r * H + kb * 32 + g * 8;
    const float4 x0 = *(const float4*)px;
    const float4 x1 = *(const float4*)(px + 4);
    bf16x8 a;
    a[0]=f2bf(x0.x); a[1]=f2bf(x0.y); a[2]=f2bf(x0.z); a[3]=f2bf(x0.w);
    a[4]=f2bf(x1.x); a[5]=f2bf(x1.y); a[6]=f2bf(x1.z); a[7]=f2bf(x1.w);
    afr[kb] = a;
  }

  const int bb = isQ ? 0 : ((row0 - 2048) >> 9);   // batch (key rows)
  const int kbase = isQ ? 0 : ((row0 - 2048) & 511);

  #pragma unroll
  for (int t = 0; t < 4; ++t) {                    // 4 h-tiles of 16
    const int hcol = t * 16 + r;
    f32x4 acc = {0.f, 0.f, 0.f, 0.f};
    #pragma unroll
    for (int kb = 0; kb < 2; ++kb) {
      bf16x8 wfr;
      #pragma unroll
      for (int j = 0; j < 8; ++j)
        wfr[j] = f2bf(Wl[(kb*32 + g*8 + j) * 65 + hcol]);
      acc = isQ ? __builtin_amdgcn_mfma_f32_16x16x32_bf16(afr[kb], wfr, acc, 0, 0, 0)
                : __builtin_amdgcn_mfma_f32_16x16x32_bf16(wfr, afr[kb], acc, 0, 0, 0);
    }
    if (isQ) {
      // D: col(=h)=lane&15, row(=q-row)=g*4+reg
      const float wvv = wv[hcol];
      #pragma unroll
      for (int rr = 0; rr < 4; ++rr) {
        const int row = row0 + g * 4 + rr;
        const float s = fminf(15.f, fmaxf(-15.f, acc[rr])) * C2LE;
        const float rq = fexp2(-s);
        qAR[(size_t)row * H + hcol] = make_float2(-2.f * wvv * rq, rq);
      }
    } else {
      // D transposed: col(=k)=lane&15, row(=h)=t*16+g*4+reg
      const int k = kbase + r;
      #pragma unroll
      for (int rr = 0; rr < 4; ++rr) {
        const int h = t * 16 + g * 4 + rr;
        const float s = fminf(15.f, fmaxf(-15.f, acc[rr])) * C2LE;
        EkT[((size_t)bb * H + h) * K + k] = fexp2(s);
      }
    }
  }
}

// ---- fused attention: one block per (b, 4 queries). 512 threads = 8 waves.
// Score phase: thread = key, lane-coalesced EkT dword loads; q operands held
// lane-distributed (lane=h) and broadcast via v_readlane (register-only, no
// memory in the hot loop). Per element: add + rcp + fma -> trans-pipe-bound.
__global__ __launch_bounds__(512) void attn_kernel(
    const float2* __restrict__ qAR, const float* __restrict__ EkT,
    const float* __restrict__ values, const int* __restrict__ vlens,
    float* __restrict__ out)
{
  __shared__ float p[4][K];          // 8KB: scores -> probs
  __shared__ float part[8][4][V];    // 8KB: PV partials
  __shared__ float red[4][2][2];     // [query][half][max,sum]

  const int tid = threadIdx.x, lane = tid & 63;
  const int wave = __builtin_amdgcn_readfirstlane(tid >> 6);
  const int b = blockIdx.x >> 4, q0 = (blockIdx.x & 15) << 2;
  const int vlen = vlens[b];

  // preload A,R: lane l holds h=l for the block's 4 queries (8 VGPRs)
  float vA[4], vR[4];
  {
    const float2* ar0 = qAR + ((size_t)b * Q + q0) * H;
    #pragma unroll
    for (int qi = 0; qi < 4; ++qi) {
      const float2 t = ar0[qi * H + lane];
      vA[qi] = t.x; vR[qi] = t.y;
    }
  }

  // ---- phase 1: scores, thread = key (tid), 4 queries x 64 h
  {
    const float* ekp = EkT + (size_t)b * H * K + tid;
    float a0 = 0.f, a1 = 0.f, a2 = 0.f, a3 = 0.f;
    #pragma unroll
    for (int hc = 0; hc < 8; ++hc) {
      float ek[8];
      #pragma unroll
      for (int j = 0; j < 8; ++j) ek[j] = ekp[(size_t)(hc * 8 + j) * K];
      #pragma unroll
      for (int j = 0; j < 8; ++j) {
        const int h = hc * 8 + j;                  // compile-time after unroll
        a0 = fmaf(rdlane(vA[0], h), frcp(rdlane(vR[0], h) + ek[j]), a0);
        a1 = fmaf(rdlane(vA[1], h), frcp(rdlane(vR[1], h) + ek[j]), a1);
        a2 = fmaf(rdlane(vA[2], h), frcp(rdlane(vR[2], h) + ek[j]), a2);
        a3 = fmaf(rdlane(vA[3], h), frcp(rdlane(vR[3], h) + ek[j]), a3);
      }
    }
    p[0][tid] = a0; p[1][tid] = a1; p[2][tid] = a2; p[3][tid] = a3;
  }
  __syncthreads();

  // ---- phase 2: masked softmax; wave = (query, half of K). 8 waves busy.
  const int qi = wave & 3, half = wave >> 2;
  const int kb2 = half * 256 + lane * 4;
  {
    float s[4];
    *(float4*)s = *(const float4*)&p[qi][kb2];
    float m = NEG;
    #pragma unroll
    for (int j = 0; j < 4; ++j) {
      s[j] = (kb2 + j < vlen) ? s[j] : NEG;
      m = fmaxf(m, s[j]);
    }
    #pragma unroll
    for (int off = 32; off; off >>= 1) m = fmaxf(m, __shfl_xor(m, off, 64));
    if (lane == 0) red[qi][half][0] = m;
    __syncthreads();
    m = fmaxf(red[qi][0][0], red[qi][1][0]);
    float sum = 0.f;
    #pragma unroll
    for (int j = 0; j < 4; ++j) { s[j] = fexp2((s[j] - m) * L2E); sum += s[j]; }
    *(float4*)&p[qi][kb2] = *(float4*)s;
    #pragma unroll
    for (int off = 32; off; off >>= 1) sum += __shfl_xor(sum, off, 64);
    if (lane == 0) red[qi][half][1] = sum;
    __syncthreads();
  }

  // ---- phase 3: PV. wave covers keys [wave*64, wave*64+64), lane = v.
  {
    const int kb = wave * 64;
    const float* vb = values + ((size_t)b * K + kb) * V + lane;
    float a0 = 0.f, a1 = 0.f, a2 = 0.f, a3 = 0.f;
    #pragma unroll 4
    for (int k4 = 0; k4 < 64; k4 += 4) {
      const float4 p0 = *(const float4*)&p[0][kb + k4];   // uniform: broadcast
      const float4 p1 = *(const float4*)&p[1][kb + k4];
      const float4 p2 = *(const float4*)&p[2][kb + k4];
      const float4 p3 = *(const float4*)&p[3][kb + k4];
      const float v0 = vb[(size_t)(k4 + 0) * V];
      const float v1 = vb[(size_t)(k4 + 1) * V];
      const float v2 = vb[(size_t)(k4 + 2) * V];
      const float v3 = vb[(size_t)(k4 + 3) * V];
      a0 = fmaf(p0.x,v0, fmaf(p0.y,v1, fmaf(p0.z,v2, fmaf(p0.w,v3, a0))));
      a1 = fmaf(p1.x,v0, fmaf(p1.y,v1, fmaf(p1.z,v2, fmaf(p1.w,v3, a1))));
      a2 = fmaf(p2.x,v0, fmaf(p2.y,v1, fmaf(p2.z,v2, fmaf(p2.w,v3, a2))));
      a3 = fmaf(p3.x,v0, fmaf(p3.y,v1, fmaf(p3.z,v2, fmaf(p3.w,v3, a3))));
    }
    part[wave][0][lane] = a0; part[wave][1][lane] = a1;
    part[wave][2][lane] = a2; part[wave][3][lane] = a3;
  }
  __syncthreads();

  // ---- phase 4: cross-wave reduce + normalize + write (waves 0..3)
  if (wave < 4) {
    const float inv = frcp(red[wave][0][1] + red[wave][1][1]);
    float o = 0.f;
    #pragma unroll
    for (int w = 0; w < 8; ++w) o += part[w][wave][lane];
    out[((size_t)b * Q + q0 + wave) * V + lane] = o * inv;
  }
}

extern "C" void kernel_launch(void* const* d_in, const int* in_sizes, int n_in,
                              void* d_out, int out_size, void* d_ws, size_t ws_size,
                              hipStream_t stream) {
  const float* queries = (const float*)d_in[0];
  const float* keys    = (const float*)d_in[1];
  const float* values  = (const float*)d_in[2];
  const int*   vlens   = (const int*)d_in[3];
  const float* Wq      = (const float*)d_in[4];
  const float* Wk      = (const float*)d_in[5];
  const float* wv      = (const float*)d_in[6];
  float* out = (float*)d_out;

  float2* qAR = (float2*)d_ws;                       // B*Q*H float2 (1MB)
  float*  EkT = (float*)(qAR + (size_t)B*Q*H);       // B*H*K floats (4MB, h-major)

  proj_kernel<<<(B*Q + B*K) / 64, 256, 0, stream>>>(queries, keys, Wq, Wk, wv, qAR, EkT);
  attn_kernel<<<B*(Q/4), 512, 0, stream>>>(qAR, EkT, values, vlens, out);
}

// Round 6
// 23.498 us; speedup vs baseline: 1.3715x; 1.3715x over previous
//
#include <hip/hip_runtime.h>

#define NEG (-1e6f)

static constexpr int B = 32, Q = 64, K = 512, H = 64, V = 64;
static constexpr float C2LE = 2.8853900817779268f;   // 2*log2(e)
static constexpr float L2E  = 1.4426950408889634f;   // log2(e)

typedef __attribute__((ext_vector_type(8))) short bf16x8;
typedef __attribute__((ext_vector_type(4))) float f32x4;

__device__ __forceinline__ float fexp2(float x) { return __builtin_amdgcn_exp2f(x); }
__device__ __forceinline__ float frcp(float x)  { return __builtin_amdgcn_rcpf(x); }

__device__ __forceinline__ unsigned short f2bf(float f) {  // RNE f32 -> bf16
  union { float f; unsigned u; } v; v.f = f;
  unsigned r = v.u + 0x7fffu + ((v.u >> 16) & 1u);
  return (unsigned short)(r >> 16);
}
__device__ __forceinline__ unsigned pack2bf(float lo, float hi) {
  return (unsigned)f2bf(lo) | ((unsigned)f2bf(hi) << 16);
}

// ---- MFMA projections + fused exponentials, vlen-skipped, XCD-affine.
// Grid 288 = 8 XCDs x 36 slots (slot 0..3: q-block of b=xcd*4+slot;
// slot 4..35: key 64-row chunk). All data for batch b produced on XCD b>>2.
// Query rows -> qAR2[b][qg][hp][qi][{A,R} x2h] with A=-2*wv_h*e^{-2q}, R=e^{-2q}
//   (16 contiguous dwords per (qg,hp) -> one s_load_dwordx16 in attn)
// Key rows   -> Ekp[b][hp][k] = {bf16(e^{2k_h0}), bf16(e^{2k_h1})} packed dword.
// wv_h*tanh(q+k) = wv_h + A*rcp(R+E); const sum(wv) dropped (softmax shift-inv).
// Clamp +-15 pre-exp (tanh saturated). MFMA 16x16x32 bf16 (m89/m91 layout);
// swapped operands transpose D so key tiles come out h-major (verified r5).
__global__ __launch_bounds__(256) void proj_kernel(
    const float* __restrict__ queries, const float* __restrict__ keys,
    const float* __restrict__ Wq, const float* __restrict__ Wk,
    const float* __restrict__ wv, const int* __restrict__ vlens,
    float* __restrict__ qAR2, unsigned* __restrict__ Ekp)
{
  __shared__ float Wl[64 * 65];                    // +1 pad: <=2-way (free)
  const int xcd = blockIdx.x & 7, slot = blockIdx.x >> 3;
  const bool isQ = slot < 4;                       // block-uniform
  const int b = isQ ? (xcd * 4 + slot) : (xcd * 4 + ((slot - 4) >> 3));
  const int kb64 = (slot - 4) & 7;
  const int vlen = vlens[b];
  if (!isQ && kb64 * 64 >= vlen) return;           // whole chunk masked

  const int tid = threadIdx.x, lane = tid & 63;
  const int wave = __builtin_amdgcn_readfirstlane(tid >> 6);
  const float* Wsrc = isQ ? Wq : Wk;
  #pragma unroll
  for (int i = 0; i < 16; ++i) {                   // stage W (coalesced)
    const int idx = tid + i * 256;
    Wl[(idx >> 6) * 65 + (idx & 63)] = Wsrc[idx];
  }
  __syncthreads();

  const int r = lane & 15, g = lane >> 4;
  const int rloc0 = (isQ ? 0 : kb64 * 64) + wave * 16;   // row-in-b of stripe
  if (!isQ && rloc0 >= vlen) return;               // after the only barrier
  const float* xbase = isQ ? (queries + ((size_t)b * Q + rloc0) * H)
                           : (keys    + ((size_t)b * K + rloc0) * H);

  bf16x8 afr[2];
  #pragma unroll
  for (int kb = 0; kb < 2; ++kb) {                 // X frag: 8 contiguous k/lane
    const float* px = xbase + (size_t)r * H + kb * 32 + g * 8;
    const float4 x0 = *(const float4*)px;
    const float4 x1 = *(const float4*)(px + 4);
    bf16x8 a;
    a[0]=f2bf(x0.x); a[1]=f2bf(x0.y); a[2]=f2bf(x0.z); a[3]=f2bf(x0.w);
    a[4]=f2bf(x1.x); a[5]=f2bf(x1.y); a[6]=f2bf(x1.z); a[7]=f2bf(x1.w);
    afr[kb] = a;
  }

  #pragma unroll
  for (int t = 0; t < 4; ++t) {                    // 4 h-tiles of 16
    const int hcol = t * 16 + r;
    f32x4 acc = {0.f, 0.f, 0.f, 0.f};
    #pragma unroll
    for (int kb = 0; kb < 2; ++kb) {
      bf16x8 wfr;
      #pragma unroll
      for (int j = 0; j < 8; ++j)
        wfr[j] = f2bf(Wl[(kb*32 + g*8 + j) * 65 + hcol]);
      acc = isQ ? __builtin_amdgcn_mfma_f32_16x16x32_bf16(afr[kb], wfr, acc, 0, 0, 0)
                : __builtin_amdgcn_mfma_f32_16x16x32_bf16(wfr, afr[kb], acc, 0, 0, 0);
    }
    if (isQ) {
      // D: col(=h)=r, row(=q-row)=g*4+reg
      const float wvv = wv[hcol];
      #pragma unroll
      for (int rr = 0; rr < 4; ++rr) {
        const int qq = rloc0 + g * 4 + rr;
        const float s = fminf(15.f, fmaxf(-15.f, acc[rr])) * C2LE;
        const float rq = fexp2(-s);
        const size_t off = (((size_t)(b*16 + (qq>>2)) * 32 + (hcol>>1)) * 16)
                           + (qq & 3) * 4 + (hcol & 1) * 2;
        *(float2*)(qAR2 + off) = make_float2(-2.f * wvv * rq, rq);
      }
    } else {
      // D transposed: col(=k)=r, row(=h)=t*16+g*4+reg; pack h-pairs as bf16x2
      const int k = rloc0 + r;
      float E[4];
      #pragma unroll
      for (int rr = 0; rr < 4; ++rr)
        E[rr] = fexp2(fminf(15.f, fmaxf(-15.f, acc[rr])) * C2LE);
      const int hp = t * 8 + g * 2;
      Ekp[((size_t)b*32 + hp    ) * 512 + k] = pack2bf(E[0], E[1]);
      Ekp[((size_t)b*32 + hp + 1) * 512 + k] = pack2bf(E[2], E[3]);
    }
  }
}

// ---- fused attention: grid 512 = 8 XCDs x 64 slots; block=(b,4 queries),
// 512 threads = 8 waves, XCD b>>2 (same as producer). Score phase: thread=key,
// bf16-pair Ek dword loads (contiguous 256B/wave), A/R via s_load_dwordx16
// from the contiguous qAR2 block. Waves with k-range >= vlen skip entirely.
__global__ __launch_bounds__(512) void attn_kernel(
    const float* __restrict__ qAR2, const unsigned* __restrict__ Ekp,
    const float* __restrict__ values, const int* __restrict__ vlens,
    float* __restrict__ out)
{
  __shared__ float p[4][K];          // 8KB: scores -> probs
  __shared__ float part[8][4][V];    // 8KB: PV partials
  __shared__ float red[4][2][2];     // [query][half][max,sum]

  const int xcd = blockIdx.x & 7, slot = blockIdx.x >> 3;
  const int b = xcd * 4 + (slot >> 4), qg = slot & 15;
  const int vlen = vlens[b];
  const int tid = threadIdx.x, lane = tid & 63;
  const int wave = __builtin_amdgcn_readfirstlane(tid >> 6);

  // ---- phase 1: scores, thread = key tid; skip waves fully past vlen
  if (wave * 64 < vlen) {
    const unsigned* ekp = Ekp + (size_t)b * 32 * 512 + tid;
    const float* ar = qAR2 +
        (size_t)__builtin_amdgcn_readfirstlane((b * 16 + qg) * 512);
    float a0 = 0.f, a1 = 0.f, a2 = 0.f, a3 = 0.f;
    #pragma unroll
    for (int hp = 0; hp < 32; ++hp) {
      const unsigned u = ekp[hp * 512];
      const float E0 = __uint_as_float(u << 16);
      const float E1 = __uint_as_float(u & 0xffff0000u);
      const float* s = ar + hp * 16;               // uniform -> s_load_dwordx16
      a0 = fmaf(s[ 0], frcp(s[ 1] + E0), a0);
      a0 = fmaf(s[ 2], frcp(s[ 3] + E1), a0);
      a1 = fmaf(s[ 4], frcp(s[ 5] + E0), a1);
      a1 = fmaf(s[ 6], frcp(s[ 7] + E1), a1);
      a2 = fmaf(s[ 8], frcp(s[ 9] + E0), a2);
      a2 = fmaf(s[10], frcp(s[11] + E1), a2);
      a3 = fmaf(s[12], frcp(s[13] + E0), a3);
      a3 = fmaf(s[14], frcp(s[15] + E1), a3);
    }
    p[0][tid] = a0; p[1][tid] = a1; p[2][tid] = a2; p[3][tid] = a3;
  }
  __syncthreads();

  // ---- phase 2: masked softmax; wave = (query, half of K). 8 waves busy.
  const int qi = wave & 3, half = wave >> 2;
  const int kb2 = half * 256 + lane * 4;
  {
    float s[4];
    *(float4*)s = *(const float4*)&p[qi][kb2];     // garbage beyond vlen: masked
    float m = NEG;
    #pragma unroll
    for (int j = 0; j < 4; ++j) {
      s[j] = (kb2 + j < vlen) ? s[j] : NEG;
      m = fmaxf(m, s[j]);
    }
    #pragma unroll
    for (int off = 32; off; off >>= 1) m = fmaxf(m, __shfl_xor(m, off, 64));
    if (lane == 0) red[qi][half][0] = m;
    __syncthreads();
    m = fmaxf(red[qi][0][0], red[qi][1][0]);
    float sum = 0.f;
    #pragma unroll
    for (int j = 0; j < 4; ++j) { s[j] = fexp2((s[j] - m) * L2E); sum += s[j]; }
    *(float4*)&p[qi][kb2] = *(float4*)s;           // zeros beyond vlen
    #pragma unroll
    for (int off = 32; off; off >>= 1) sum += __shfl_xor(sum, off, 64);
    if (lane == 0) red[qi][half][1] = sum;
    __syncthreads();
  }

  // ---- phase 3: PV. wave covers keys [wave*64, wave*64+64), lane = v.
  {
    const int kb = wave * 64;
    if (kb < vlen) {
      const float* vb = values + ((size_t)b * K + kb) * V + lane;
      float a0 = 0.f, a1 = 0.f, a2 = 0.f, a3 = 0.f;
      #pragma unroll 4
      for (int k4 = 0; k4 < 64; k4 += 4) {
        const float4 p0 = *(const float4*)&p[0][kb + k4];  // uniform: broadcast
        const float4 p1 = *(const float4*)&p[1][kb + k4];
        const float4 p2 = *(const float4*)&p[2][kb + k4];
        const float4 p3 = *(const float4*)&p[3][kb + k4];
        const float v0 = vb[(size_t)(k4 + 0) * V];
        const float v1 = vb[(size_t)(k4 + 1) * V];
        const float v2 = vb[(size_t)(k4 + 2) * V];
        const float v3 = vb[(size_t)(k4 + 3) * V];
        a0 = fmaf(p0.x,v0, fmaf(p0.y,v1, fmaf(p0.z,v2, fmaf(p0.w,v3, a0))));
        a1 = fmaf(p1.x,v0, fmaf(p1.y,v1, fmaf(p1.z,v2, fmaf(p1.w,v3, a1))));
        a2 = fmaf(p2.x,v0, fmaf(p2.y,v1, fmaf(p2.z,v2, fmaf(p2.w,v3, a2))));
        a3 = fmaf(p3.x,v0, fmaf(p3.y,v1, fmaf(p3.z,v2, fmaf(p3.w,v3, a3))));
      }
      part[wave][0][lane] = a0; part[wave][1][lane] = a1;
      part[wave][2][lane] = a2; part[wave][3][lane] = a3;
    } else {
      part[wave][0][lane] = 0.f; part[wave][1][lane] = 0.f;
      part[wave][2][lane] = 0.f; part[wave][3][lane] = 0.f;
    }
  }
  __syncthreads();

  // ---- phase 4: cross-wave reduce + normalize + write (waves 0..3)
  if (wave < 4) {
    const float inv = frcp(red[wave][0][1] + red[wave][1][1]);
    float o = 0.f;
    #pragma unroll
    for (int w = 0; w < 8; ++w) o += part[w][wave][lane];
    out[((size_t)b * Q + qg * 4 + wave) * V + lane] = o * inv;
  }
}

extern "C" void kernel_launch(void* const* d_in, const int* in_sizes, int n_in,
                              void* d_out, int out_size, void* d_ws, size_t ws_size,
                              hipStream_t stream) {
  const float* queries = (const float*)d_in[0];
  const float* keys    = (const float*)d_in[1];
  const float* values  = (const float*)d_in[2];
  const int*   vlens   = (const int*)d_in[3];
  const float* Wq      = (const float*)d_in[4];
  const float* Wk      = (const float*)d_in[5];
  const float* wv      = (const float*)d_in[6];
  float* out = (float*)d_out;

  float*    qAR2 = (float*)d_ws;                        // B*16*32*16 floats (1MB)
  unsigned* Ekp  = (unsigned*)(qAR2 + (size_t)B*16*32*16); // B*32*512 dwords (2MB)

  proj_kernel<<<288, 256, 0, stream>>>(queries, keys, Wq, Wk, wv, vlens, qAR2, Ekp);
  attn_kernel<<<512, 512, 0, stream>>>(qAR2, Ekp, values, vlens, out);
}